// Round 1
// baseline (515.851 us; speedup 1.0000x reference)
//
#include <hip/hip_runtime.h>
#include <hip/hip_bf16.h>

#define B_ 2
#define S_ 2048
#define E_ 1024
#define H_ 16
#define D_ 64

typedef __bf16 bf16x8 __attribute__((ext_vector_type(8)));
typedef __bf16 bf16x4 __attribute__((ext_vector_type(4)));
typedef float f32x4 __attribute__((ext_vector_type(4)));

// ws layout in bf16 elements:
//   x_bf     : [4096, 1024]        offset 0         (4194304)
//   qkvw_bf  : [3072, 1024]        offset 4194304   (3145728)
//   projw_bf : [1024, 1024]        offset 7340032   (1048576)
//   qkv_bf   : [3][B,H,S,D]        offset 8388608   (3*4194304)
//   attn_bf  : [4096, 1024]        offset 20971520  (4194304)
// total 25165824 elem = 48 MiB

__device__ __forceinline__ f32x4 mfma16(bf16x8 a, bf16x8 b, f32x4 c) {
    return __builtin_amdgcn_mfma_f32_16x16x32_bf16(a, b, c, 0, 0, 0);
}

__global__ __launch_bounds__(256) void convert_kernel(
        const float* __restrict__ x, const float* __restrict__ qkvw,
        const float* __restrict__ projw, __bf16* __restrict__ ws) {
    const long NX = 4194304, NW = 3145728;
    long i = (long)(blockIdx.x * 256 + threadIdx.x) * 4;
    const float* src; __bf16* dst; long off;
    if (i < NX)           { src = x;     dst = ws;           off = i; }
    else if (i < NX + NW) { src = qkvw;  dst = ws + NX;      off = i - NX; }
    else                  { src = projw; dst = ws + NX + NW; off = i - NX - NW; }
    float4 v = *(const float4*)(src + off);
    bf16x4 o = { (__bf16)v.x, (__bf16)v.y, (__bf16)v.z, (__bf16)v.w };
    *(bf16x4*)(dst + off) = o;
}

// C[M,N] = A[M,K] @ W[N,K]^T + bias, scatter into qkv (3,B,H,S,D) bf16
__global__ __launch_bounds__(256) void qkv_gemm(
        const __bf16* __restrict__ xbf, const __bf16* __restrict__ wbf,
        const float* __restrict__ bias, __bf16* __restrict__ qkv) {
    const int K = E_;
    int wave = threadIdx.x >> 6, lane = threadIdx.x & 63;
    int quad = lane >> 4, lm = lane & 15;
    int rowT = blockIdx.x * 128 + wave * 32;
    int colT = blockIdx.y * 64;
    f32x4 acc[2][4] = {};
    const __bf16* aptr = xbf + (long)(rowT + lm) * K + quad * 8;
    const __bf16* bptr = wbf + (long)(colT + lm) * K + quad * 8;
    for (int k0 = 0; k0 < K; k0 += 32) {
        bf16x8 af[2], bfr[4];
        for (int wm = 0; wm < 2; wm++)
            af[wm] = *(const bf16x8*)(aptr + (long)wm * 16 * K + k0);
        for (int wn = 0; wn < 4; wn++)
            bfr[wn] = *(const bf16x8*)(bptr + (long)wn * 16 * K + k0);
        for (int wm = 0; wm < 2; wm++)
            for (int wn = 0; wn < 4; wn++)
                acc[wm][wn] = mfma16(af[wm], bfr[wn], acc[wm][wn]);
    }
    for (int wn = 0; wn < 4; wn++) {
        int col = colT + wn * 16 + lm;
        float bv = bias[col];
        int which = col >> 10, rem = col & 1023;
        int h = rem >> 6, d = rem & 63;
        for (int wm = 0; wm < 2; wm++) {
            int rowb = rowT + wm * 16 + quad * 4;
            for (int r = 0; r < 4; r++) {
                int row = rowb + r;
                int b = row >> 11, s = row & 2047;
                float v = acc[wm][wn][r] + bv;
                qkv[(long)((which * B_ + b) * H_ + h) * (S_ * D_) + (long)s * D_ + d] = (__bf16)v;
            }
        }
    }
}

__global__ __launch_bounds__(256) void flash_attn(
        const __bf16* __restrict__ qkv, const int* __restrict__ mask,
        __bf16* __restrict__ attn) {
    int wave = threadIdx.x >> 6, lane = threadIdx.x & 63;
    int quad = lane >> 4, lm = lane & 15;
    int qtile = blockIdx.x;   // 0..31
    int bh = blockIdx.y;      // 0..31
    int b = bh >> 4, h = bh & 15;
    const long BHSD = (long)B_ * H_ * S_ * D_;
    const __bf16* qp = qkv + (long)bh * (S_ * D_);
    const __bf16* kp = qkv + BHSD + (long)bh * (S_ * D_);
    const __bf16* vp = qkv + 2 * BHSD + (long)bh * (S_ * D_);
    const int* mrow = mask + b * S_;

    int q0 = qtile * 64 + wave * 16;
    bf16x8 qa[2];
    for (int t = 0; t < 2; t++)
        qa[t] = *(const bf16x8*)(qp + (long)(q0 + lm) * D_ + t * 32 + quad * 8);

    f32x4 O[4] = {};
    float m_run[4], l_run[4];
    for (int r = 0; r < 4; r++) { m_run[r] = -1e30f; l_run[r] = 0.f; }

    __shared__ __bf16 Plds[4][16][40];   // pad 32->40 to spread banks

    for (int kb = 0; kb < S_; kb += 32) {
        f32x4 sf[2];
        for (int hh = 0; hh < 2; hh++) {
            const __bf16* krow = kp + (long)(kb + hh * 16 + lm) * D_ + quad * 8;
            bf16x8 kf0 = *(const bf16x8*)(krow);
            bf16x8 kf1 = *(const bf16x8*)(krow + 32);
            f32x4 z = {};
            z = mfma16(qa[0], kf0, z);
            sf[hh] = mfma16(qa[1], kf1, z);
        }
        int mk0 = mrow[kb + lm];
        int mk1 = mrow[kb + 16 + lm];
        float p[2][4], vmax[4];
        for (int r = 0; r < 4; r++) {
            float s0 = mk0 ? sf[0][r] * 0.125f : -1e30f;
            float s1 = mk1 ? sf[1][r] * 0.125f : -1e30f;
            p[0][r] = s0; p[1][r] = s1;
            vmax[r] = fmaxf(s0, s1);
        }
        for (int off = 1; off < 16; off <<= 1)
            for (int r = 0; r < 4; r++)
                vmax[r] = fmaxf(vmax[r], __shfl_xor(vmax[r], off));
        float alpha[4], rs[4];
        for (int r = 0; r < 4; r++) {
            float mn = fmaxf(m_run[r], vmax[r]);
            alpha[r] = __expf(m_run[r] - mn);
            m_run[r] = mn;
            p[0][r] = __expf(p[0][r] - mn);
            p[1][r] = __expf(p[1][r] - mn);
            rs[r] = p[0][r] + p[1][r];
        }
        for (int off = 1; off < 16; off <<= 1)
            for (int r = 0; r < 4; r++)
                rs[r] += __shfl_xor(rs[r], off);
        for (int r = 0; r < 4; r++) l_run[r] = l_run[r] * alpha[r] + rs[r];
        for (int c = 0; c < 4; c++)
            for (int r = 0; r < 4; r++)
                O[c][r] *= alpha[r];
        // P: C-layout -> LDS -> A-layout
        for (int hh = 0; hh < 2; hh++)
            for (int r = 0; r < 4; r++)
                Plds[wave][quad * 4 + r][hh * 16 + lm] = (__bf16)p[hh][r];
        __syncthreads();
        bf16x8 pa = *(const bf16x8*)(&Plds[wave][lm][quad * 8]);
        for (int c = 0; c < 4; c++) {
            bf16x8 vf;
            for (int j = 0; j < 8; j++)
                vf[j] = vp[(long)(kb + quad * 8 + j) * D_ + c * 16 + lm];
            O[c] = mfma16(pa, vf, O[c]);
        }
        __syncthreads();
    }
    float inv[4];
    for (int r = 0; r < 4; r++) inv[r] = (l_run[r] > 0.f) ? 1.f / l_run[r] : 0.f;
    for (int c = 0; c < 4; c++)
        for (int r = 0; r < 4; r++) {
            int s = q0 + quad * 4 + r;
            int e = h * 64 + c * 16 + lm;
            attn[(long)(b * S_ + s) * E_ + e] = (__bf16)(O[c][r] * inv[r]);
        }
}

// out[M,N] = A[M,K] @ W[N,K]^T + bias, fp32 out
__global__ __launch_bounds__(256) void proj_gemm(
        const __bf16* __restrict__ abf, const __bf16* __restrict__ wbf,
        const float* __restrict__ bias, float* __restrict__ out) {
    const int K = E_;
    int wave = threadIdx.x >> 6, lane = threadIdx.x & 63;
    int quad = lane >> 4, lm = lane & 15;
    int rowT = blockIdx.x * 128 + wave * 32;
    int colT = blockIdx.y * 64;
    f32x4 acc[2][4] = {};
    const __bf16* aptr = abf + (long)(rowT + lm) * K + quad * 8;
    const __bf16* bptr = wbf + (long)(colT + lm) * K + quad * 8;
    for (int k0 = 0; k0 < K; k0 += 32) {
        bf16x8 af[2], bfr[4];
        for (int wm = 0; wm < 2; wm++)
            af[wm] = *(const bf16x8*)(aptr + (long)wm * 16 * K + k0);
        for (int wn = 0; wn < 4; wn++)
            bfr[wn] = *(const bf16x8*)(bptr + (long)wn * 16 * K + k0);
        for (int wm = 0; wm < 2; wm++)
            for (int wn = 0; wn < 4; wn++)
                acc[wm][wn] = mfma16(af[wm], bfr[wn], acc[wm][wn]);
    }
    for (int wn = 0; wn < 4; wn++) {
        int col = colT + wn * 16 + lm;
        float bv = bias[col];
        for (int wm = 0; wm < 2; wm++) {
            int rowb = rowT + wm * 16 + quad * 4;
            for (int r = 0; r < 4; r++) {
                int row = rowb + r;
                out[(long)row * E_ + col] = acc[wm][wn][r] + bv;
            }
        }
    }
}

extern "C" void kernel_launch(void* const* d_in, const int* in_sizes, int n_in,
                              void* d_out, int out_size, void* d_ws, size_t ws_size,
                              hipStream_t stream) {
    const float* x      = (const float*)d_in[0];
    const int*   mask   = (const int*)d_in[1];
    const float* qkv_w  = (const float*)d_in[2];
    const float* qkv_b  = (const float*)d_in[3];
    const float* proj_w = (const float*)d_in[4];
    const float* proj_b = (const float*)d_in[5];
    float* out = (float*)d_out;
    __bf16* ws = (__bf16*)d_ws;

    __bf16* x_bf     = ws;
    __bf16* qkvw_bf  = ws + 4194304;
    __bf16* projw_bf = ws + 7340032;
    __bf16* qkv_bf   = ws + 8388608;
    __bf16* attn_bf  = ws + 20971520;

    convert_kernel<<<8192, 256, 0, stream>>>(x, qkv_w, proj_w, ws);
    qkv_gemm<<<dim3(32, 48), 256, 0, stream>>>(x_bf, qkvw_bf, qkv_b, qkv_bf);
    flash_attn<<<dim3(32, 32), 256, 0, stream>>>(qkv_bf, mask, attn_bf);
    proj_gemm<<<dim3(32, 16), 256, 0, stream>>>(attn_bf, projw_bf, proj_b, out);
}

// Round 2
// 497.084 us; speedup vs baseline: 1.0378x; 1.0378x over previous
//
#include <hip/hip_runtime.h>
#include <hip/hip_bf16.h>

#define B_ 2
#define S_ 2048
#define E_ 1024
#define H_ 16
#define D_ 64

typedef __bf16 bf16x8 __attribute__((ext_vector_type(8)));
typedef __bf16 bf16x4 __attribute__((ext_vector_type(4)));
typedef float f32x4 __attribute__((ext_vector_type(4)));

// ws layout in bf16 elements:
//   x_bf     : [4096, 1024]        offset 0         (4194304)
//   qkvw_bf  : [3072, 1024]        offset 4194304   (3145728)
//   projw_bf : [1024, 1024]        offset 7340032   (1048576)
//   qk_bf    : [2][B,H,S,D]        offset 8388608   (8388608)
//   vt_bf    : [B,H,D,S]           offset 16777216  (4194304)
//   attn_bf  : [4096, 1024]        offset 20971520  (4194304)
// total 25165824 elem = 48 MiB

__device__ __forceinline__ f32x4 mfma16(bf16x8 a, bf16x8 b, f32x4 c) {
    return __builtin_amdgcn_mfma_f32_16x16x32_bf16(a, b, c, 0, 0, 0);
}

__global__ __launch_bounds__(256) void convert_kernel(
        const float* __restrict__ x, const float* __restrict__ qkvw,
        const float* __restrict__ projw, __bf16* __restrict__ ws) {
    const long NX = 4194304, NW = 3145728;
    long i = (long)(blockIdx.x * 256 + threadIdx.x) * 4;
    const float* src; __bf16* dst; long off;
    if (i < NX)           { src = x;     dst = ws;           off = i; }
    else if (i < NX + NW) { src = qkvw;  dst = ws + NX;      off = i - NX; }
    else                  { src = projw; dst = ws + NX + NW; off = i - NX - NW; }
    float4 v = *(const float4*)(src + off);
    bf16x4 o = { (__bf16)v.x, (__bf16)v.y, (__bf16)v.z, (__bf16)v.w };
    *(bf16x4*)(dst + off) = o;
}

// Q,K only: C[t, col] = x[t,:] @ qkv_w[col,:]^T + b  for col in [0, 2048)
__global__ __launch_bounds__(256) void qkv_gemm(
        const __bf16* __restrict__ xbf, const __bf16* __restrict__ wbf,
        const float* __restrict__ bias, __bf16* __restrict__ qk) {
    const int K = E_;
    int wave = threadIdx.x >> 6, lane = threadIdx.x & 63;
    int quad = lane >> 4, lm = lane & 15;
    int rowT = blockIdx.x * 128 + wave * 32;
    int colT = blockIdx.y * 64;
    f32x4 acc[2][4] = {};
    const __bf16* aptr = xbf + (long)(rowT + lm) * K + quad * 8;
    const __bf16* bptr = wbf + (long)(colT + lm) * K + quad * 8;
    for (int k0 = 0; k0 < K; k0 += 32) {
        bf16x8 af[2], bfr[4];
        for (int wm = 0; wm < 2; wm++)
            af[wm] = *(const bf16x8*)(aptr + (long)wm * 16 * K + k0);
        for (int wn = 0; wn < 4; wn++)
            bfr[wn] = *(const bf16x8*)(bptr + (long)wn * 16 * K + k0);
        for (int wm = 0; wm < 2; wm++)
            for (int wn = 0; wn < 4; wn++)
                acc[wm][wn] = mfma16(af[wm], bfr[wn], acc[wm][wn]);
    }
    for (int wn = 0; wn < 4; wn++) {
        int col = colT + wn * 16 + lm;
        float bv = bias[col];
        int which = col >> 10, rem = col & 1023;
        int h = rem >> 6, d = rem & 63;
        for (int wm = 0; wm < 2; wm++) {
            int rowb = rowT + wm * 16 + quad * 4;
            for (int r = 0; r < 4; r++) {
                int row = rowb + r;
                int b = row >> 11, s = row & 2047;
                float v = acc[wm][wn][r] + bv;
                qk[(long)((which * B_ + b) * H_ + h) * (S_ * D_) + (long)s * D_ + d] = (__bf16)v;
            }
        }
    }
}

// VT[(b,h,d), t] = sum_k Wv[h*64+d, k] * x[t, k] + bias_v  -> [B,H,D,S] bf16
__global__ __launch_bounds__(256) void vt_gemm(
        const __bf16* __restrict__ xbf, const __bf16* __restrict__ wvbf,
        const float* __restrict__ bias, __bf16* __restrict__ vt) {
    const int K = E_;
    int wave = threadIdx.x >> 6, lane = threadIdx.x & 63;
    int quad = lane >> 4, lm = lane & 15;
    int rowT = blockIdx.x * 128 + wave * 32;   // M = 1024 (v-row)
    int colT = blockIdx.y * 64;                // N = 4096 (token)
    f32x4 acc[2][4] = {};
    const __bf16* aptr = wvbf + (long)(rowT + lm) * K + quad * 8;
    const __bf16* bptr = xbf + (long)(colT + lm) * K + quad * 8;
    for (int k0 = 0; k0 < K; k0 += 32) {
        bf16x8 af[2], bfr[4];
        for (int wm = 0; wm < 2; wm++)
            af[wm] = *(const bf16x8*)(aptr + (long)wm * 16 * K + k0);
        for (int wn = 0; wn < 4; wn++)
            bfr[wn] = *(const bf16x8*)(bptr + (long)wn * 16 * K + k0);
        for (int wm = 0; wm < 2; wm++)
            for (int wn = 0; wn < 4; wn++)
                acc[wm][wn] = mfma16(af[wm], bfr[wn], acc[wm][wn]);
    }
    for (int wn = 0; wn < 4; wn++) {
        int t = colT + wn * 16 + lm;
        int b = t >> 11, s = t & 2047;
        for (int wm = 0; wm < 2; wm++) {
            int rowb = rowT + wm * 16 + quad * 4;
            for (int r = 0; r < 4; r++) {
                int m = rowb + r;          // v-row: h*64+d
                int h = m >> 6, d = m & 63;
                float v = acc[wm][wn][r] + bias[2048 + m];
                vt[(long)((b * H_ + h) * D_ + d) * S_ + s] = (__bf16)v;
            }
        }
    }
}

__global__ __launch_bounds__(256) void flash_attn(
        const __bf16* __restrict__ qk, const __bf16* __restrict__ vt,
        const int* __restrict__ mask, __bf16* __restrict__ attn) {
    int wave = threadIdx.x >> 6, lane = threadIdx.x & 63;
    int quad = lane >> 4, lm = lane & 15;
    int qtile = blockIdx.x;   // 0..31
    int bh = blockIdx.y;      // 0..31
    int b = bh >> 4, h = bh & 15;
    const long BHSD = (long)B_ * H_ * S_ * D_;
    const __bf16* qp  = qk + (long)bh * (S_ * D_);
    const __bf16* kp  = qk + BHSD + (long)bh * (S_ * D_);
    const __bf16* vtp = vt + (long)bh * (D_ * S_);   // [d][s]
    const int* mrow = mask + b * S_;

    int q0 = qtile * 64 + wave * 16;
    bf16x8 qa[2];
    for (int t = 0; t < 2; t++)
        qa[t] = *(const bf16x8*)(qp + (long)(q0 + lm) * D_ + t * 32 + quad * 8);

    f32x4 O[4] = {};
    float m_run[4], l_run[4];
    for (int r = 0; r < 4; r++) { m_run[r] = -1e30f; l_run[r] = 0.f; }

    __shared__ __bf16 Plds[4][16][72];   // wave-private; stride 72 to spread banks

    for (int kb = 0; kb < S_; kb += 64) {
        // QK^T: 64 keys
        f32x4 sf[4];
        for (int hh = 0; hh < 4; hh++) {
            const __bf16* krow = kp + (long)(kb + hh * 16 + lm) * D_ + quad * 8;
            bf16x8 kf0 = *(const bf16x8*)(krow);
            bf16x8 kf1 = *(const bf16x8*)(krow + 32);
            f32x4 z = {};
            z = mfma16(qa[0], kf0, z);
            sf[hh] = mfma16(qa[1], kf1, z);
        }
        int mk[4];
        for (int hh = 0; hh < 4; hh++) mk[hh] = mrow[kb + hh * 16 + lm];
        float p[4][4], vmax[4];
        for (int r = 0; r < 4; r++) vmax[r] = -1e30f;
        for (int hh = 0; hh < 4; hh++)
            for (int r = 0; r < 4; r++) {
                float s = mk[hh] ? sf[hh][r] * 0.125f : -1e30f;
                p[hh][r] = s;
                vmax[r] = fmaxf(vmax[r], s);
            }
        for (int off = 1; off < 16; off <<= 1)
            for (int r = 0; r < 4; r++)
                vmax[r] = fmaxf(vmax[r], __shfl_xor(vmax[r], off));
        float alpha[4], rs[4];
        for (int r = 0; r < 4; r++) {
            float mn = fmaxf(m_run[r], vmax[r]);
            alpha[r] = __expf(m_run[r] - mn);
            m_run[r] = mn;
            float acc = 0.f;
            for (int hh = 0; hh < 4; hh++) {
                p[hh][r] = __expf(p[hh][r] - mn);
                acc += p[hh][r];
            }
            rs[r] = acc;
        }
        for (int off = 1; off < 16; off <<= 1)
            for (int r = 0; r < 4; r++)
                rs[r] += __shfl_xor(rs[r], off);
        for (int r = 0; r < 4; r++) l_run[r] = l_run[r] * alpha[r] + rs[r];
        for (int c = 0; c < 4; c++)
            for (int r = 0; r < 4; r++)
                O[c][r] *= alpha[r];
        // P: C-layout -> LDS -> A-layout (wave-private slice, no barrier needed)
        for (int hh = 0; hh < 4; hh++)
            for (int r = 0; r < 4; r++)
                Plds[wave][quad * 4 + r][hh * 16 + lm] = (__bf16)p[hh][r];
        bf16x8 pa0 = *(const bf16x8*)(&Plds[wave][lm][quad * 8]);
        bf16x8 pa1 = *(const bf16x8*)(&Plds[wave][lm][32 + quad * 8]);
        // PV: V^T rows are contiguous in s -> vector B-fragment loads
        for (int c = 0; c < 4; c++) {
            const __bf16* vrow = vtp + (long)(c * 16 + lm) * S_ + kb + quad * 8;
            bf16x8 vf0 = *(const bf16x8*)(vrow);
            bf16x8 vf1 = *(const bf16x8*)(vrow + 32);
            O[c] = mfma16(pa0, vf0, O[c]);
            O[c] = mfma16(pa1, vf1, O[c]);
        }
    }
    float inv[4];
    for (int r = 0; r < 4; r++) inv[r] = (l_run[r] > 0.f) ? 1.f / l_run[r] : 0.f;
    for (int c = 0; c < 4; c++)
        for (int r = 0; r < 4; r++) {
            int s = q0 + quad * 4 + r;
            int e = h * 64 + c * 16 + lm;
            attn[(long)(b * S_ + s) * E_ + e] = (__bf16)(O[c][r] * inv[r]);
        }
}

// out[M,N] = A[M,K] @ W[N,K]^T + bias, fp32 out
__global__ __launch_bounds__(256) void proj_gemm(
        const __bf16* __restrict__ abf, const __bf16* __restrict__ wbf,
        const float* __restrict__ bias, float* __restrict__ out) {
    const int K = E_;
    int wave = threadIdx.x >> 6, lane = threadIdx.x & 63;
    int quad = lane >> 4, lm = lane & 15;
    int rowT = blockIdx.x * 128 + wave * 32;
    int colT = blockIdx.y * 64;
    f32x4 acc[2][4] = {};
    const __bf16* aptr = abf + (long)(rowT + lm) * K + quad * 8;
    const __bf16* bptr = wbf + (long)(colT + lm) * K + quad * 8;
    for (int k0 = 0; k0 < K; k0 += 32) {
        bf16x8 af[2], bfr[4];
        for (int wm = 0; wm < 2; wm++)
            af[wm] = *(const bf16x8*)(aptr + (long)wm * 16 * K + k0);
        for (int wn = 0; wn < 4; wn++)
            bfr[wn] = *(const bf16x8*)(bptr + (long)wn * 16 * K + k0);
        for (int wm = 0; wm < 2; wm++)
            for (int wn = 0; wn < 4; wn++)
                acc[wm][wn] = mfma16(af[wm], bfr[wn], acc[wm][wn]);
    }
    for (int wn = 0; wn < 4; wn++) {
        int col = colT + wn * 16 + lm;
        float bv = bias[col];
        for (int wm = 0; wm < 2; wm++) {
            int rowb = rowT + wm * 16 + quad * 4;
            for (int r = 0; r < 4; r++) {
                int row = rowb + r;
                out[(long)row * E_ + col] = acc[wm][wn][r] + bv;
            }
        }
    }
}

extern "C" void kernel_launch(void* const* d_in, const int* in_sizes, int n_in,
                              void* d_out, int out_size, void* d_ws, size_t ws_size,
                              hipStream_t stream) {
    const float* x      = (const float*)d_in[0];
    const int*   mask   = (const int*)d_in[1];
    const float* qkv_w  = (const float*)d_in[2];
    const float* qkv_b  = (const float*)d_in[3];
    const float* proj_w = (const float*)d_in[4];
    const float* proj_b = (const float*)d_in[5];
    float* out = (float*)d_out;
    __bf16* ws = (__bf16*)d_ws;

    __bf16* x_bf     = ws;
    __bf16* qkvw_bf  = ws + 4194304;
    __bf16* projw_bf = ws + 7340032;
    __bf16* qk_bf    = ws + 8388608;
    __bf16* vt_bf    = ws + 16777216;
    __bf16* attn_bf  = ws + 20971520;

    convert_kernel<<<8192, 256, 0, stream>>>(x, qkv_w, proj_w, ws);
    qkv_gemm<<<dim3(32, 32), 256, 0, stream>>>(x_bf, qkvw_bf, qkv_b, qk_bf);
    vt_gemm<<<dim3(8, 64), 256, 0, stream>>>(x_bf, qkvw_bf + 2 * E_ * E_, qkv_b, vt_bf);
    flash_attn<<<dim3(32, 32), 256, 0, stream>>>(qk_bf, vt_bf, mask, attn_bf);
    proj_gemm<<<dim3(32, 16), 256, 0, stream>>>(attn_bf, projw_bf, proj_b, out);
}